// Round 12
// baseline (288.635 us; speedup 1.0000x reference)
//
#include <hip/hip_runtime.h>
#include <stdint.h>

typedef __attribute__((ext_vector_type(8))) short short8;
typedef __attribute__((ext_vector_type(4))) float floatx4;

#define MFMA16(a, b, c) __builtin_amdgcn_mfma_f32_16x16x32_bf16(a, b, c, 0, 0, 0)

// Pack two fp32 -> bf16 pair (lo, hi) in ONE v_perm_b32 after +0x8000
// round-half-up (vs software RNE: ~10 VALU -> 3 VALU per pair).
__device__ __forceinline__ unsigned pkbf(float lo, float hi) {
    const unsigned a = __builtin_bit_cast(unsigned, lo) + 0x8000u;
    const unsigned b = __builtin_bit_cast(unsigned, hi) + 0x8000u;
    return __builtin_amdgcn_perm(b, a, 0x07060302u);  // {b.hi16, a.hi16}
}
__device__ __forceinline__ unsigned short f2bf(float x) {
    unsigned u = __builtin_bit_cast(unsigned, x);
    u = (u + 0x7fffu + ((u >> 16) & 1u)) >> 16;  // RNE (cold paths only)
    return (unsigned short)u;
}

// Activation tiles are 64x128 bf16 viewed as u32 pairs: u32 index u of a row
// holds bf16 cols (2u, 2u+1). 16B chunks XOR-swizzled by row&15: b32 C-layout
// writes stay <=2-way (free), b128 A-frag reads are bank-balanced.
__device__ __forceinline__ int hphys(int row, int u) {
    return row * 64 + ((((u >> 2) ^ (row & 15)) << 2) | (u & 3));
}

// Grid: 2048 WGs; WG owns batch rows [2*bx, 2*bx+2) — fwd, bwd and init all
// accumulate in LDS (accT), one coalesced writeout, no global atomics.
// == R12: the untested budget cell — waves_per_eu(3,3) = 170-reg budget ==
// REGISTER MODEL (R1-R11): live set ~145-150 unified regs. Under the 128
// budget (waves_per_eu(4,4)) it spills ~5-25 dwords (R5/R8/R9); under 256
// (waves_per_eu(2)) runtime caps at 2 waves/SIMD (22% occ). 170 = zero
// spill AND 3 waves/SIMD (37.5% ~= the measured 39% of the 128-budget
// binaries, minus the spill-reload stalls). The slack re-enables R10's
// feats-staging overlap (correct mechanism — deletes the per-tile serial
// staging region — it failed under 128 only because +10 live regs = spill):
// tile-0 staged at dir setup, feats(tt+1) staged inside the L3 phase,
// ping-pong fbuf. ds_add_f32 accT accumulate + no-div L3 index kept.
// N-split: wave w owns hidden cols [32w,32w+32) for layers 1-2 (W1/W2 B-frags
// in regs; even/odd col pairing -> packed b32 LDS writes). Layer 3 M-split,
// w3f in regs. sw==c identity folds the A-frag swizzle to base ^ (k<<2).
// W2 staged per-dir through sbuf with the R6 rot-map (verified 0 conflicts).
__global__ __launch_bounds__(256)
__attribute__((amdgpu_waves_per_eu(3, 3)))
void NeuralNet_37615323578557_kernel(
        const float* __restrict__ x, const float* __restrict__ t,
        const float* __restrict__ fW1, const float* __restrict__ fb1,
        const float* __restrict__ fW2, const float* __restrict__ fb2,
        const float* __restrict__ fW3, const float* __restrict__ fb3,
        const float* __restrict__ gW1, const float* __restrict__ gb1,
        const float* __restrict__ gW2, const float* __restrict__ gb2,
        const float* __restrict__ gW3, const float* __restrict__ gb3,
        const float* __restrict__ iW1, const float* __restrict__ ib1,
        const float* __restrict__ iW2, const float* __restrict__ ib2,
        const float* __restrict__ iW3, const float* __restrict__ ib3,
        float* __restrict__ out) {
    __shared__ unsigned sbuf[8192];             // 32 KB: h1 | h2 (or W2 image)
    __shared__ unsigned short fbuf[2][64 * 8];  // 2 KB feats ping-pong
    __shared__ float accT[2 * 256 * 2];         // 4 KB output accumulator

    unsigned* const h1buf = sbuf;               // 16 KB (64 rows x 64 u32)
    unsigned* const h2buf = sbuf + 4096;        // 16 KB

    const int tid  = threadIdx.x;
    const int lane = tid & 63;
    const int w    = tid >> 6;      // wave 0..3
    const int c    = lane & 15;     // MFMA low index (m for A, n for B/C)
    const int q    = lane >> 4;     // MFMA quad
    const int b0   = blockIdx.x * 2;

    // ---- zero the output accumulator ----
    #pragma unroll
    for (int k = 0; k < 4; ++k) accT[tid + k * 256] = 0.0f;
    __syncthreads();

    // ---- init MLP: waves 0,1 handle b_local = w (pure fp32 VALU) ----
    // Scratch = fbuf[0] (512 B/wave); readers drain before the dir-top
    // barrier, so dir-0's tile-0 staging (also fbuf[0]) is safely ordered.
    if (w < 2) {
        float* h1s = (float*)&fbuf[0][0] + w * 128;
        const int b = b0 + w;
        const float* xb = x + (size_t)b * 514;
        const float f0 = xb[0], f1 = xb[1], f2 = t[b];
        const int u0 = lane, u1 = lane + 64;
        const float h0 = fmaxf(iW1[u0] * f0 + iW1[128 + u0] * f1 + iW1[256 + u0] * f2 + ib1[u0], 0.f);
        const float h1 = fmaxf(iW1[u1] * f0 + iW1[128 + u1] * f1 + iW1[256 + u1] * f2 + ib1[u1], 0.f);
        h1s[u0] = h0;
        h1s[u1] = h1;
        float a0 = ib2[lane], a1 = ib2[lane + 64];
        for (int k = 0; k < 128; ++k) {
            const float hv = h1s[k];
            a0 += hv * iW2[k * 128 + lane];
            a1 += hv * iW2[k * 128 + lane + 64];
        }
        a0 = fmaxf(a0, 0.f); a1 = fmaxf(a1, 0.f);
        float p0 = a0 * iW3[lane * 2 + 0] + a1 * iW3[(lane + 64) * 2 + 0];
        float p1 = a0 * iW3[lane * 2 + 1] + a1 * iW3[(lane + 64) * 2 + 1];
        #pragma unroll
        for (int m = 1; m < 64; m <<= 1) {
            p0 += __shfl_xor(p0, m, 64);
            p1 += __shfl_xor(p1, m, 64);
        }
        if (lane == 0) {
            accT[w * 512 + 0] += p0 + ib3[0];
            accT[w * 512 + 1] += p1 + ib3[1];
        }
    }

    const int wbase = w * 32;
    const int ucol  = w * 16 + c;   // u32 col index this lane writes

    for (int dir = 0; dir < 2; ++dir) {
        const float* W1 = dir ? gW1 : fW1;
        const float* B1 = dir ? gb1 : fb1;
        const float* W2 = dir ? gW2 : fW2;
        const float* B2 = dir ? gb2 : fb2;
        const float* W3 = dir ? gW3 : fW3;
        const float* B3 = dir ? gb3 : fb3;
        const int posoff = (1 - dir) * 2;

        __syncthreads();  // prev dir's sbuf/fbuf readers (and init) drained

        // ---- stage W2 B-frag image into sbuf (exactly 32 KB) ----
        // Element (k,n) -> block B=((n>>5)*2+(n&1))*4+(k>>5),
        //   ushort idx = B*512 + (((k>>3)&3)*16 + ((n>>1)&15))*8 + (k&7).
        // Thread t: rows {k0,k0+1} with k0=2(t&63), cols [c0,c0+32) with
        // float2-rotation -> write bank covers all 32 (R6: verified 0
        // conflicts). unroll 4 caps in-flight loads at 8 payload regs.
        {
            const int k0  = (tid & 63) << 1;
            const int c0  = (tid >> 6) << 5;
            const int rot = (tid >> 2) & 15;
            const int ks  = k0 >> 5;
            const int q2  = (k0 >> 3) & 3;
            const int j0  = k0 & 7;         // even
            const float* r0p = &W2[k0 * 128 + c0];
            const float* r1p = r0p + 128;
            const int usb = (q2 << 4) * 8 + j0;   // + B*512 + n2*8
            #pragma unroll 4
            for (int nn2 = 0; nn2 < 16; ++nn2) {
                const int off = ((nn2 + rot) & 15) << 1;
                const float2 v0 = *(const float2*)(r0p + off);
                const float2 v1 = *(const float2*)(r1p + off);
                #pragma unroll
                for (int e = 0; e < 2; ++e) {
                    const int n = c0 + off + e;
                    const unsigned pv = pkbf(e ? v0.y : v0.x, e ? v1.y : v1.x);
                    const int B = ((n >> 5) * 2 + (n & 1)) * 4 + ks;
                    const int us = B * 512 + ((n >> 1) & 15) * 8 + usb;
                    sbuf[us >> 1] = pv;
                }
            }
        }

        // ---- small weight frags (W1, W3, biases) straight to regs ----
        short8 w1f[2], w3f[4];
        float  b1v[2], b2v[2];
        #pragma unroll
        for (int ntl = 0; ntl < 2; ++ntl) {
            const int col = wbase + 2 * c + ntl;
            b1v[ntl] = B1[col];
            b2v[ntl] = B2[col];
            short8 f = {0, 0, 0, 0, 0, 0, 0, 0};
            if (q == 0) {  // K padded 8 -> 32: only quad 0 holds real W1 rows
                #pragma unroll
                for (int j = 0; j < 8; ++j) f[j] = (short)f2bf(W1[j * 128 + col]);
            }
            w1f[ntl] = f;
        }
        const float b3c = (c < 2) ? B3[c] : 0.0f;
        #pragma unroll
        for (int ks = 0; ks < 4; ++ks) {  // W3: N padded 2 -> 16
            short8 f = {0, 0, 0, 0, 0, 0, 0, 0};
            if (c < 2) {
                #pragma unroll
                for (int j = 0; j < 8; ++j)
                    f[j] = (short)f2bf(W3[(ks * 32 + q * 8 + j) * 2 + c]);
            }
            w3f[ks] = f;
        }
        __syncthreads();  // W2 frag image complete

        // ---- w2f from LDS: 8 conflict-free ds_read_b128 per lane ----
        short8 w2f[2][4];
        {
            const unsigned short* img = (const unsigned short*)sbuf;
            #pragma unroll
            for (int ntl = 0; ntl < 2; ++ntl)
                #pragma unroll
                for (int ks = 0; ks < 4; ++ks)
                    w2f[ntl][ks] = *(const short8*)
                        &img[(((w * 2 + ntl) * 4 + ks) << 9) + lane * 8];
        }
        // (w2f reads complete before the first in-loop barrier -> sbuf safe
        //  to overwrite with h1 after that barrier)

        // ---- stage tile-0 feats into fbuf[0]: lane<16 of each wave ----
        // fbuf[0]'s last readers (init / prev dir L1 of tt=6) drained at or
        // before the dir-top barrier; first in-loop barrier orders these
        // writes before tile-0's L1 reads.
        if (lane < 16) {
            const int r = w * 16 + lane;     // 0..63, always < 510
            const float* xb = x + (size_t)b0 * 514;
            const float2 xi  = *(const float2*)(xb + 2 * r);
            const float2 xi1 = *(const float2*)(xb + 2 * r + 2);
            const float2 pt  = *(const float2*)(xb + 512);
            const float tv = t[b0];
            const float nv = (float)(dir ? r : (r + 1)) * (1.0f / 256.0f);
            unsigned* fp = (unsigned*)&fbuf[0][r * 8];
            if (dir == 0) {
                fp[0] = pkbf(xi1.x, xi1.y);
                fp[1] = pkbf(tv, xi.x);
                fp[2] = pkbf(xi.y, nv);
            } else {
                fp[0] = pkbf(xi.x, xi.y);
                fp[1] = pkbf(tv, xi1.x);
                fp[2] = pkbf(xi1.y, nv);
            }
            fp[3] = pkbf(pt.x, pt.y);
        }

        #pragma unroll 1
        for (int tt = 0; tt < 8; ++tt) {
            const int r0 = tt * 64;
            const unsigned short* ftile = &fbuf[tt & 1][0];

            __syncthreads();  // feats(tt) ready; prev L2 h1-reads drained

            // ---- layer 1: h1[cols wbase..wbase+32) for 64 rows ----
            #pragma unroll
            for (int mt = 0; mt < 4; ++mt) {
                short8 af = {0, 0, 0, 0, 0, 0, 0, 0};
                if (q == 0) af = *(const short8*)&ftile[(mt * 16 + c) * 8];
                floatx4 a0 = {b1v[0], b1v[0], b1v[0], b1v[0]};
                floatx4 a1 = {b1v[1], b1v[1], b1v[1], b1v[1]};
                a0 = MFMA16(af, w1f[0], a0);
                a1 = MFMA16(af, w1f[1], a1);
                const int rowb = mt * 16 + q * 4;
                #pragma unroll
                for (int rr = 0; rr < 4; ++rr)
                    h1buf[hphys(rowb + rr, ucol)] =
                        pkbf(fmaxf(a0[rr], 0.0f), fmaxf(a1[rr], 0.0f));
            }
            __syncthreads();  // h1 complete

            // ---- layer 2: read h1, write h2 (disjoint halves) ----
            // row = mt*16 + c -> row&15 == c, so the XOR swizzle folds to
            // base = (q^c)<<2 and (k+q)^c = base ^ (k<<2) for k in {4,8,12}.
            #pragma unroll
            for (int mt = 0; mt < 4; ++mt) {
                const unsigned* rp = &h1buf[(mt * 16 + c) * 64];
                const int base = (q ^ c) << 2;
                short8 a0 = *(const short8*)&rp[base];
                short8 a1 = *(const short8*)&rp[base ^ 16];
                short8 a2 = *(const short8*)&rp[base ^ 32];
                short8 a3 = *(const short8*)&rp[base ^ 48];
                floatx4 s0 = {b2v[0], b2v[0], b2v[0], b2v[0]};
                floatx4 s1 = {b2v[1], b2v[1], b2v[1], b2v[1]};
                s0 = MFMA16(a0, w2f[0][0], s0); s1 = MFMA16(a0, w2f[1][0], s1);
                s0 = MFMA16(a1, w2f[0][1], s0); s1 = MFMA16(a1, w2f[1][1], s1);
                s0 = MFMA16(a2, w2f[0][2], s0); s1 = MFMA16(a2, w2f[1][2], s1);
                s0 = MFMA16(a3, w2f[0][3], s0); s1 = MFMA16(a3, w2f[1][3], s1);
                const int rowb = mt * 16 + q * 4;
                #pragma unroll
                for (int rr = 0; rr < 4; ++rr)
                    h2buf[hphys(rowb + rr, ucol)] =
                        pkbf(fmaxf(s0[rr], 0.0f), fmaxf(s1[rr], 0.0f));
            }
            __syncthreads();  // h2 complete

            // ---- layer 3 + stage feats(tt+1) (overlapped) ----
            {
                // stage next tile's features: lane<16 of each wave, 1 row.
                // fbuf[(tt+1)&1]'s last readers (L1 of tile tt-1) drained
                // >=2 barriers ago.
                if (tt < 7 && lane < 16) {
                    const int r = r0 + 64 + w * 16 + lane;
                    unsigned v0 = 0, v1 = 0, v2 = 0, v3 = 0;
                    if (r < 510) {
                        const int bl = (r >= 255) ? 1 : 0;
                        const int i  = r - bl * 255;
                        const float* xb = x + (size_t)(b0 + bl) * 514;
                        const float2 xi  = *(const float2*)(xb + 2 * i);
                        const float2 xi1 = *(const float2*)(xb + 2 * i + 2);
                        const float2 pt  = *(const float2*)(xb + 512);
                        const float tv = t[b0 + bl];
                        const float nv = (float)(dir ? i : (i + 1)) * (1.0f / 256.0f);
                        if (dir == 0) {
                            v0 = pkbf(xi1.x, xi1.y);
                            v1 = pkbf(tv, xi.x);
                            v2 = pkbf(xi.y, nv);
                        } else {
                            v0 = pkbf(xi.x, xi.y);
                            v1 = pkbf(tv, xi1.x);
                            v2 = pkbf(xi1.y, nv);
                        }
                        v3 = pkbf(pt.x, pt.y);
                    }
                    unsigned* fp = (unsigned*)&fbuf[(tt + 1) & 1][(w * 16 + lane) * 8];
                    fp[0] = v0; fp[1] = v1; fp[2] = v2; fp[3] = v3;
                }

                // layer 3: wave owns rows [16w,16w+16); ds_add into accT
                const unsigned* rp = &h2buf[(w * 16 + c) * 64];
                const int base = (q ^ c) << 2;
                short8 a0 = *(const short8*)&rp[base];
                short8 a1 = *(const short8*)&rp[base ^ 16];
                short8 a2 = *(const short8*)&rp[base ^ 32];
                short8 a3 = *(const short8*)&rp[base ^ 48];
                floatx4 s = {b3c, b3c, b3c, b3c};
                s = MFMA16(a0, w3f[0], s);
                s = MFMA16(a1, w3f[1], s);
                s = MFMA16(a2, w3f[2], s);
                s = MFMA16(a3, w3f[3], s);
                if (c < 2) {
                    const int rb = r0 + w * 16 + q * 4;
                    #pragma unroll
                    for (int rr = 0; rr < 4; ++rr) {
                        const int r = rb + rr;
                        if (r < 510) {
                            // idx = 512*bl + 2*pos + c, pos = (r-255bl)+1-dir
                            //     = 2r + 2*(r>=255) + 2(1-dir) + c  (no div)
                            const int idx = 2 * r + ((r >= 255) ? 2 : 0)
                                          + posoff + c;
                            atomicAdd(&accT[idx], s[rr]);  // ds_add_f32
                        }
                    }
                }
            }
            // next tile's h1/h2 writes ordered by its own barriers
        }
    }

    __syncthreads();  // accT complete (ds_add ordered by barrier)
    // ---- coalesced writeout: 1024 floats = out[b0..b0+1] ----
    ((float4*)(out + (size_t)b0 * 512))[tid] = ((const float4*)accT)[tid];
}

extern "C" void kernel_launch(void* const* d_in, const int* in_sizes, int n_in,
                              void* d_out, int out_size, void* d_ws, size_t ws_size,
                              hipStream_t stream) {
    (void)in_sizes; (void)n_in; (void)d_ws; (void)ws_size; (void)out_size;
    const float* x   = (const float*)d_in[0];
    const float* t   = (const float*)d_in[1];
    const float* fW1 = (const float*)d_in[2];
    const float* fb1 = (const float*)d_in[3];
    const float* fW2 = (const float*)d_in[4];
    const float* fb2 = (const float*)d_in[5];
    const float* fW3 = (const float*)d_in[6];
    const float* fb3 = (const float*)d_in[7];
    const float* gW1 = (const float*)d_in[8];
    const float* gb1 = (const float*)d_in[9];
    const float* gW2 = (const float*)d_in[10];
    const float* gb2 = (const float*)d_in[11];
    const float* gW3 = (const float*)d_in[12];
    const float* gb3 = (const float*)d_in[13];
    const float* iW1 = (const float*)d_in[14];
    const float* ib1 = (const float*)d_in[15];
    const float* iW2 = (const float*)d_in[16];
    const float* ib2 = (const float*)d_in[17];
    const float* iW3 = (const float*)d_in[18];
    const float* ib3 = (const float*)d_in[19];
    float* out = (float*)d_out;

    NeuralNet_37615323578557_kernel<<<dim3(2048), 256, 0, stream>>>(
        x, t, fW1, fb1, fW2, fb2, fW3, fb3,
        gW1, gb1, gW2, gb2, gW3, gb3,
        iW1, ib1, iW2, ib2, iW3, ib3, out);
}

// Round 13
// 262.843 us; speedup vs baseline: 1.0981x; 1.0981x over previous
//
#include <hip/hip_runtime.h>
#include <stdint.h>

typedef __attribute__((ext_vector_type(8))) short short8;
typedef __attribute__((ext_vector_type(4))) float floatx4;

#define MFMA16(a, b, c) __builtin_amdgcn_mfma_f32_16x16x32_bf16(a, b, c, 0, 0, 0)

// Pack two fp32 -> bf16 pair (lo, hi) in ONE v_perm_b32 after +0x8000
// round-half-up (vs software RNE: ~10 VALU -> 3 VALU per pair).
__device__ __forceinline__ unsigned pkbf(float lo, float hi) {
    const unsigned a = __builtin_bit_cast(unsigned, lo) + 0x8000u;
    const unsigned b = __builtin_bit_cast(unsigned, hi) + 0x8000u;
    return __builtin_amdgcn_perm(b, a, 0x07060302u);  // {b.hi16, a.hi16}
}
__device__ __forceinline__ unsigned short f2bf(float x) {
    unsigned u = __builtin_bit_cast(unsigned, x);
    u = (u + 0x7fffu + ((u >> 16) & 1u)) >> 16;  // RNE (cold paths only)
    return (unsigned short)u;
}

// Activation tiles are 64x128 bf16 viewed as u32 pairs: u32 index u of a row
// holds bf16 cols (2u, 2u+1). 16B chunks XOR-swizzled by row&15: b32 C-layout
// writes stay <=2-way (free), b128 A-frag reads are bank-balanced.
__device__ __forceinline__ int hphys(int row, int u) {
    return row * 64 + ((((u >> 2) ^ (row & 15)) << 2) | (u & 3));
}

// Grid: 2048 WGs; WG owns batch rows [2*bx, 2*bx+2) — fwd, bwd and init all
// accumulate in LDS (accT), one coalesced writeout, no global atomics.
// == R13 = R11 (205 us) + w3f evicted to a 512 B LDS image ==
// COMPLETED BUDGET MATRIX (R1-R12): 2 waves/SIMD clean = 287 us; 3 waves
// clean = 220 us (ragged 768+768+512 batch tail at 3 WGs/CU); 4 waves +
// ~20 MB spill = 205 us. Near-linear wave scaling => 4 waves CLEAN ~ 185.
// The live set misses the 128-reg (4,4) budget by ~16 regs: exactly w3f.
// Evict it to LDS (R8 mechanism — correctness-verified there; R8's
// regression was its fully-unrolled staging loop spilling 98 MB, fixed
// since R9 by unroll 4). Cost: 4 broadcast ds_read_b128/wave-tile.
// 2048 WGs at 4 WGs/CU = perfect 1024x2 batch packing.
// N-split: wave w owns hidden cols [32w,32w+32) for layers 1-2 (W1/W2 B-frags
// in regs; even/odd col pairing -> packed b32 LDS writes). Layer 3 M-split.
// sw==c identity folds the A-frag swizzle to base ^ (k<<2). W2 staged
// per-dir through sbuf with the R6 rot-map (verified 0 conflicts).
// ds_add_f32 accT accumulate + no-div L3 index (both register-neutral).
__global__ __launch_bounds__(256)
__attribute__((amdgpu_waves_per_eu(4, 4)))
void NeuralNet_37615323578557_kernel(
        const float* __restrict__ x, const float* __restrict__ t,
        const float* __restrict__ fW1, const float* __restrict__ fb1,
        const float* __restrict__ fW2, const float* __restrict__ fb2,
        const float* __restrict__ fW3, const float* __restrict__ fb3,
        const float* __restrict__ gW1, const float* __restrict__ gb1,
        const float* __restrict__ gW2, const float* __restrict__ gb2,
        const float* __restrict__ gW3, const float* __restrict__ gb3,
        const float* __restrict__ iW1, const float* __restrict__ ib1,
        const float* __restrict__ iW2, const float* __restrict__ ib2,
        const float* __restrict__ iW3, const float* __restrict__ ib3,
        float* __restrict__ out) {
    __shared__ unsigned sbuf[8192];             // 32 KB: h1 | h2 (or W2 image)
    __shared__ unsigned short fbuf[64 * 8];     // 1 KB feats / init scratch
    __shared__ float accT[2 * 256 * 2];         // 4 KB output accumulator
    __shared__ unsigned short w3img[256];       // 512 B W3 B-frag image

    unsigned* const h1buf = sbuf;               // 16 KB (64 rows x 64 u32)
    unsigned* const h2buf = sbuf + 4096;        // 16 KB

    const int tid  = threadIdx.x;
    const int lane = tid & 63;
    const int w    = tid >> 6;      // wave 0..3
    const int c    = lane & 15;     // MFMA low index (m for A, n for B/C)
    const int q    = lane >> 4;     // MFMA quad
    const int b0   = blockIdx.x * 2;

    // ---- zero the output accumulator ----
    #pragma unroll
    for (int k = 0; k < 4; ++k) accT[tid + k * 256] = 0.0f;
    __syncthreads();

    // ---- init MLP: waves 0,1 handle b_local = w (pure fp32 VALU) ----
    // Scratch = fbuf (512 B/wave); sbuf stays free for dir-0 W2 staging.
    if (w < 2) {
        float* h1s = (float*)fbuf + w * 128;
        const int b = b0 + w;
        const float* xb = x + (size_t)b * 514;
        const float f0 = xb[0], f1 = xb[1], f2 = t[b];
        const int u0 = lane, u1 = lane + 64;
        const float h0 = fmaxf(iW1[u0] * f0 + iW1[128 + u0] * f1 + iW1[256 + u0] * f2 + ib1[u0], 0.f);
        const float h1 = fmaxf(iW1[u1] * f0 + iW1[128 + u1] * f1 + iW1[256 + u1] * f2 + ib1[u1], 0.f);
        h1s[u0] = h0;
        h1s[u1] = h1;
        float a0 = ib2[lane], a1 = ib2[lane + 64];
        for (int k = 0; k < 128; ++k) {
            const float hv = h1s[k];
            a0 += hv * iW2[k * 128 + lane];
            a1 += hv * iW2[k * 128 + lane + 64];
        }
        a0 = fmaxf(a0, 0.f); a1 = fmaxf(a1, 0.f);
        float p0 = a0 * iW3[lane * 2 + 0] + a1 * iW3[(lane + 64) * 2 + 0];
        float p1 = a0 * iW3[lane * 2 + 1] + a1 * iW3[(lane + 64) * 2 + 1];
        #pragma unroll
        for (int m = 1; m < 64; m <<= 1) {
            p0 += __shfl_xor(p0, m, 64);
            p1 += __shfl_xor(p1, m, 64);
        }
        if (lane == 0) {
            accT[w * 512 + 0] += p0 + ib3[0];
            accT[w * 512 + 1] += p1 + ib3[1];
        }
    }

    const int wbase = w * 32;
    const int ucol  = w * 16 + c;   // u32 col index this lane writes

    for (int dir = 0; dir < 2; ++dir) {
        const float* W1 = dir ? gW1 : fW1;
        const float* B1 = dir ? gb1 : fb1;
        const float* W2 = dir ? gW2 : fW2;
        const float* B2 = dir ? gb2 : fb2;
        const float* W3 = dir ? gW3 : fW3;
        const float* B3 = dir ? gb3 : fb3;
        const int posoff = (1 - dir) * 2;

        __syncthreads();  // prev dir's sbuf/w3img reads / init fbuf done

        // ---- stage W2 B-frag image into sbuf (exactly 32 KB) ----
        // Element (k,n) -> block B=((n>>5)*2+(n&1))*4+(k>>5),
        //   ushort idx = B*512 + (((k>>3)&3)*16 + ((n>>1)&15))*8 + (k&7).
        // Thread t: rows {k0,k0+1} with k0=2(t&63), cols [c0,c0+32) with
        // float2-rotation -> write bank covers all 32 (R6: verified 0
        // conflicts). unroll 4 caps in-flight loads at 8 payload regs
        // (full unroll = 64 regs = the R5/R8 spill spike).
        {
            const int k0  = (tid & 63) << 1;
            const int c0  = (tid >> 6) << 5;
            const int rot = (tid >> 2) & 15;
            const int ks  = k0 >> 5;
            const int q2  = (k0 >> 3) & 3;
            const int j0  = k0 & 7;         // even
            const float* r0p = &W2[k0 * 128 + c0];
            const float* r1p = r0p + 128;
            const int usb = (q2 << 4) * 8 + j0;   // + B*512 + n2*8
            #pragma unroll 4
            for (int nn2 = 0; nn2 < 16; ++nn2) {
                const int off = ((nn2 + rot) & 15) << 1;
                const float2 v0 = *(const float2*)(r0p + off);
                const float2 v1 = *(const float2*)(r1p + off);
                #pragma unroll
                for (int e = 0; e < 2; ++e) {
                    const int n = c0 + off + e;
                    const unsigned pv = pkbf(e ? v0.y : v0.x, e ? v1.y : v1.x);
                    const int B = ((n >> 5) * 2 + (n & 1)) * 4 + ks;
                    const int us = B * 512 + ((n >> 1) & 15) * 8 + usb;
                    sbuf[us >> 1] = pv;
                }
            }
        }

        // ---- stage W3 B-frag image (512 B; k-pair per thread) ----
        // u32 idx = ks*32 + q2*8 + c2*4 + jp (= tid for tid<128); lane (q,c)
        // later reads ushort base (q*2 + (c&1))*8 + ks*64. (R8-verified.)
        if (tid < 128) {
            const int ks3 = tid >> 5, q3 = (tid >> 3) & 3;
            const int c3 = (tid >> 2) & 1, jp = tid & 3;
            const int k = ks3 * 32 + q3 * 8 + jp * 2;
            ((unsigned*)w3img)[tid] = pkbf(W3[k * 2 + c3], W3[(k + 1) * 2 + c3]);
        }

        // ---- small weight frags (W1, biases) straight to regs ----
        short8 w1f[2];
        float  b1v[2], b2v[2];
        #pragma unroll
        for (int ntl = 0; ntl < 2; ++ntl) {
            const int col = wbase + 2 * c + ntl;
            b1v[ntl] = B1[col];
            b2v[ntl] = B2[col];
            short8 f = {0, 0, 0, 0, 0, 0, 0, 0};
            if (q == 0) {  // K padded 8 -> 32: only quad 0 holds real W1 rows
                #pragma unroll
                for (int j = 0; j < 8; ++j) f[j] = (short)f2bf(W1[j * 128 + col]);
            }
            w1f[ntl] = f;
        }
        const float b3c = (c < 2) ? B3[c] : 0.0f;
        __syncthreads();  // W2/W3 frag images complete

        // ---- w2f from LDS: 8 conflict-free ds_read_b128 per lane ----
        short8 w2f[2][4];
        {
            const unsigned short* img = (const unsigned short*)sbuf;
            #pragma unroll
            for (int ntl = 0; ntl < 2; ++ntl)
                #pragma unroll
                for (int ks = 0; ks < 4; ++ks)
                    w2f[ntl][ks] = *(const short8*)
                        &img[(((w * 2 + ntl) * 4 + ks) << 9) + lane * 8];
        }
        // (w2f reads complete before the feats barrier below -> sbuf safe to
        //  overwrite with h1 after that barrier)

        #pragma unroll 1
        for (int tt = 0; tt < 8; ++tt) {
            const int r0 = tt * 64;

            // ---- stage features: row r -> (b_local, i) ----
            if (tid < 64) {
                const int r = r0 + tid;
                unsigned v0 = 0, v1 = 0, v2 = 0, v3 = 0;
                if (r < 510) {
                    const int bl = (r >= 255) ? 1 : 0;
                    const int i  = r - bl * 255;
                    const float* xb = x + (size_t)(b0 + bl) * 514;
                    const float2 xi  = *(const float2*)(xb + 2 * i);
                    const float2 xi1 = *(const float2*)(xb + 2 * i + 2);
                    const float2 pt  = *(const float2*)(xb + 512);   // x[b,T,:]
                    const float tv = t[b0 + bl];
                    const float nv = (float)(dir ? i : (i + 1)) * (1.0f / 256.0f);
                    if (dir == 0) {  // [x_{i+1}, t, x_i, (i+1)/T, pt]
                        v0 = pkbf(xi1.x, xi1.y);
                        v1 = pkbf(tv, xi.x);
                        v2 = pkbf(xi.y, nv);
                    } else {         // [x_i, t, x_{i+1}, i/T, pt]
                        v0 = pkbf(xi.x, xi.y);
                        v1 = pkbf(tv, xi1.x);
                        v2 = pkbf(xi1.y, nv);
                    }
                    v3 = pkbf(pt.x, pt.y);
                }
                unsigned* fp = (unsigned*)&fbuf[tid * 8];
                fp[0] = v0; fp[1] = v1; fp[2] = v2; fp[3] = v3;
            }
            __syncthreads();  // feats ready; w2f reads drained

            // ---- layer 1: h1[cols wbase..wbase+32) for 64 rows ----
            #pragma unroll
            for (int mt = 0; mt < 4; ++mt) {
                short8 af = {0, 0, 0, 0, 0, 0, 0, 0};
                if (q == 0) af = *(const short8*)&fbuf[(mt * 16 + c) * 8];
                floatx4 a0 = {b1v[0], b1v[0], b1v[0], b1v[0]};
                floatx4 a1 = {b1v[1], b1v[1], b1v[1], b1v[1]};
                a0 = MFMA16(af, w1f[0], a0);
                a1 = MFMA16(af, w1f[1], a1);
                const int rowb = mt * 16 + q * 4;
                #pragma unroll
                for (int rr = 0; rr < 4; ++rr)
                    h1buf[hphys(rowb + rr, ucol)] =
                        pkbf(fmaxf(a0[rr], 0.0f), fmaxf(a1[rr], 0.0f));
            }
            __syncthreads();  // h1 complete

            // ---- layer 2: read h1, write h2 (disjoint halves) ----
            // row = mt*16 + c -> row&15 == c, so the XOR swizzle folds to
            // base = (q^c)<<2 and (k+q)^c = base ^ (k<<2) for k in {4,8,12}.
            #pragma unroll
            for (int mt = 0; mt < 4; ++mt) {
                const unsigned* rp = &h1buf[(mt * 16 + c) * 64];
                const int base = (q ^ c) << 2;
                short8 a0 = *(const short8*)&rp[base];
                short8 a1 = *(const short8*)&rp[base ^ 16];
                short8 a2 = *(const short8*)&rp[base ^ 32];
                short8 a3 = *(const short8*)&rp[base ^ 48];
                floatx4 s0 = {b2v[0], b2v[0], b2v[0], b2v[0]};
                floatx4 s1 = {b2v[1], b2v[1], b2v[1], b2v[1]};
                s0 = MFMA16(a0, w2f[0][0], s0); s1 = MFMA16(a0, w2f[1][0], s1);
                s0 = MFMA16(a1, w2f[0][1], s0); s1 = MFMA16(a1, w2f[1][1], s1);
                s0 = MFMA16(a2, w2f[0][2], s0); s1 = MFMA16(a2, w2f[1][2], s1);
                s0 = MFMA16(a3, w2f[0][3], s0); s1 = MFMA16(a3, w2f[1][3], s1);
                const int rowb = mt * 16 + q * 4;
                #pragma unroll
                for (int rr = 0; rr < 4; ++rr)
                    h2buf[hphys(rowb + rr, ucol)] =
                        pkbf(fmaxf(s0[rr], 0.0f), fmaxf(s1[rr], 0.0f));
            }
            __syncthreads();  // h2 complete

            // ---- layer 3: wave owns rows [16w,16w+16); ds_add into accT ----
            // W3 B-frags from the 512 B LDS image: 4 ds_read_b128, 8
            // distinct addrs + 8-way same-addr broadcast (conflict-free).
            // Lanes c>=2 read the (c&1) image: they pollute only C columns
            // c>=2, which are never read.
            {
                const unsigned* rp = &h2buf[(w * 16 + c) * 64];
                const int base = (q ^ c) << 2;
                short8 a0 = *(const short8*)&rp[base];
                short8 a1 = *(const short8*)&rp[base ^ 16];
                short8 a2 = *(const short8*)&rp[base ^ 32];
                short8 a3 = *(const short8*)&rp[base ^ 48];
                const unsigned short* w3p = w3img + ((q * 2 + (c & 1)) << 3);
                floatx4 s = {b3c, b3c, b3c, b3c};
                s = MFMA16(a0, *(const short8*)&w3p[0],   s);
                s = MFMA16(a1, *(const short8*)&w3p[64],  s);
                s = MFMA16(a2, *(const short8*)&w3p[128], s);
                s = MFMA16(a3, *(const short8*)&w3p[192], s);
                if (c < 2) {
                    const int rb = r0 + w * 16 + q * 4;
                    #pragma unroll
                    for (int rr = 0; rr < 4; ++rr) {
                        const int r = rb + rr;
                        if (r < 510) {
                            // idx = 512*bl + 2*pos + c, pos = (r-255bl)+1-dir
                            //     = 2r + 2*(r>=255) + 2(1-dir) + c  (no div)
                            const int idx = 2 * r + ((r >= 255) ? 2 : 0)
                                          + posoff + c;
                            atomicAdd(&accT[idx], s[rr]);  // ds_add_f32
                        }
                    }
                }
            }
            // next tile's h1/h2 writes ordered by its own barriers
        }
    }

    __syncthreads();  // accT complete (ds_add ordered by barrier)
    // ---- coalesced writeout: 1024 floats = out[b0..b0+1] ----
    ((float4*)(out + (size_t)b0 * 512))[tid] = ((const float4*)accT)[tid];
}

extern "C" void kernel_launch(void* const* d_in, const int* in_sizes, int n_in,
                              void* d_out, int out_size, void* d_ws, size_t ws_size,
                              hipStream_t stream) {
    (void)in_sizes; (void)n_in; (void)d_ws; (void)ws_size; (void)out_size;
    const float* x   = (const float*)d_in[0];
    const float* t   = (const float*)d_in[1];
    const float* fW1 = (const float*)d_in[2];
    const float* fb1 = (const float*)d_in[3];
    const float* fW2 = (const float*)d_in[4];
    const float* fb2 = (const float*)d_in[5];
    const float* fW3 = (const float*)d_in[6];
    const float* fb3 = (const float*)d_in[7];
    const float* gW1 = (const float*)d_in[8];
    const float* gb1 = (const float*)d_in[9];
    const float* gW2 = (const float*)d_in[10];
    const float* gb2 = (const float*)d_in[11];
    const float* gW3 = (const float*)d_in[12];
    const float* gb3 = (const float*)d_in[13];
    const float* iW1 = (const float*)d_in[14];
    const float* ib1 = (const float*)d_in[15];
    const float* iW2 = (const float*)d_in[16];
    const float* ib2 = (const float*)d_in[17];
    const float* iW3 = (const float*)d_in[18];
    const float* ib3 = (const float*)d_in[19];
    float* out = (float*)d_out;

    NeuralNet_37615323578557_kernel<<<dim3(2048), 256, 0, stream>>>(
        x, t, fW1, fb1, fW2, fb2, fW3, fb3,
        gW1, gb1, gW2, gb2, gW3, gb3,
        iW1, ib1, iW2, ib2, iW3, ib3, out);
}